// Round 1
// baseline (348.809 us; speedup 1.0000x reference)
//
#include <hip/hip_runtime.h>
#include <stdint.h>

#define N_SEQ 2048
#define QKFV_COLS 2048

typedef __attribute__((ext_vector_type(8))) __bf16 bf16x8;
typedef __attribute__((ext_vector_type(4))) float f32x4;

__device__ __forceinline__ f32x4 mfma16(bf16x8 a, bf16x8 b, f32x4 c) {
  return __builtin_amdgcn_mfma_f32_16x16x32_bf16(a, b, c, 0, 0, 0);
}

__device__ __forceinline__ void glds16(const void* g, void* l) {
  __builtin_amdgcn_global_load_lds(
      (__attribute__((address_space(1))) uint32_t*)(uintptr_t)g,
      (__attribute__((address_space(3))) uint32_t*)l, 16, 0, 0);
}

// ---------------- cast / transpose ----------------
__global__ __launch_bounds__(256) void cast_bf16_kernel(const float* __restrict__ in,
                                                        __bf16* __restrict__ out, int n8) {
  int i = blockIdx.x * 256 + threadIdx.x;
  if (i >= n8) return;
  const float* p = in + (size_t)i * 8;
  bf16x8 o;
#pragma unroll
  for (int j = 0; j < 8; ++j) o[j] = (__bf16)p[j];
  *(bf16x8*)(out + (size_t)i * 8) = o;
}

// in[R][C] (f32) -> out[C][R] (bf16)
__global__ __launch_bounds__(256) void transpose_cast_kernel(const float* __restrict__ in,
                                                             __bf16* __restrict__ out,
                                                             int R, int C) {
  int i = blockIdx.x * 256 + threadIdx.x;
  int nchunks = C * (R / 8);
  if (i >= nchunks) return;
  int c = i / (R / 8);
  int r0 = (i % (R / 8)) * 8;
  bf16x8 o;
#pragma unroll
  for (int j = 0; j < 8; ++j) o[j] = (__bf16)in[(size_t)(r0 + j) * C + c];
  *(bf16x8*)(out + (size_t)c * R + r0) = o;
}

// ---------------- GEMM: C[M][N] = A[M][K] @ Bt[N][K]^T ----------------
template<typename OUT_T, bool BIAS>
__global__ __launch_bounds__(256) void gemm_bt_kernel(const __bf16* __restrict__ A,
                                                      const __bf16* __restrict__ Bt,
                                                      OUT_T* __restrict__ C,
                                                      const float* __restrict__ bias,
                                                      int M, int N, int K) {
  __shared__ alignas(16) __bf16 As[128 * 32];
  __shared__ alignas(16) __bf16 Bs[128 * 32];
  const int t = threadIdx.x;
  const int w = t >> 6;
  const int lane = t & 63;
  const int ln = lane & 15;
  const int hi8 = (lane >> 4) * 8;
  const int g4 = (lane >> 4) * 4;
  const int wr = w >> 1, wc = w & 1;
  const int m0 = blockIdx.x * 128, n0 = blockIdx.y * 128;

  f32x4 acc[4][4];
#pragma unroll
  for (int m = 0; m < 4; ++m)
#pragma unroll
    for (int n = 0; n < 4; ++n) acc[m][n] = (f32x4){0.f, 0.f, 0.f, 0.f};

  const int nk = K >> 5;
  for (int kt = 0; kt < nk; ++kt) {
    const int k0 = kt << 5;
#pragma unroll
    for (int i = 0; i < 2; ++i) {
      int c = i * 256 + t;
      int r = c >> 2, cc = c & 3;
      glds16(A + (size_t)(m0 + r) * K + k0 + cc * 8, &As[(i * 256 + w * 64) * 8]);
      glds16(Bt + (size_t)(n0 + r) * K + k0 + cc * 8, &Bs[(i * 256 + w * 64) * 8]);
    }
    __syncthreads();
    bf16x8 af[4], bfr[4];
#pragma unroll
    for (int m = 0; m < 4; ++m) af[m] = *(const bf16x8*)&As[(wr * 64 + m * 16 + ln) * 32 + hi8];
#pragma unroll
    for (int n = 0; n < 4; ++n) bfr[n] = *(const bf16x8*)&Bs[(wc * 64 + n * 16 + ln) * 32 + hi8];
#pragma unroll
    for (int m = 0; m < 4; ++m)
#pragma unroll
      for (int n = 0; n < 4; ++n) acc[m][n] = mfma16(af[m], bfr[n], acc[m][n]);
    __syncthreads();
  }

#pragma unroll
  for (int m = 0; m < 4; ++m)
#pragma unroll
    for (int n = 0; n < 4; ++n) {
      int col = n0 + wc * 64 + n * 16 + ln;
      float bv = BIAS ? bias[col] : 0.f;
#pragma unroll
      for (int r = 0; r < 4; ++r) {
        int row = m0 + wr * 64 + m * 16 + g4 + r;
        C[(size_t)row * N + col] = (OUT_T)(acc[m][n][r] + bv);
      }
    }
}

// ---------------- fv: fvb[bh][d][e] += sum_n f[n,d] * v[n,e] ----------------
__global__ __launch_bounds__(256) void fv_kernel(const __bf16* __restrict__ qkfv,
                                                 float* __restrict__ fvb) {
  __shared__ alignas(16) float Ft[64 * 64];
  __shared__ alignas(16) float Vt[64 * 64];
  const int t = threadIdx.x;
  const int bh = blockIdx.y;
  const int b = bh >> 3, h = bh & 7;
  const int n0 = blockIdx.x * 128;
  const int d = t >> 2;
  const int e0 = (t & 3) * 16;
  f32x4 acc[4];
#pragma unroll
  for (int k = 0; k < 4; ++k) acc[k] = (f32x4){0.f, 0.f, 0.f, 0.f};

  for (int tile = 0; tile < 2; ++tile) {
    const int nb = n0 + tile * 64;
    __syncthreads();
#pragma unroll
    for (int i = 0; i < 2; ++i) {
      int c = i * 256 + t;
      int r = c >> 3, cc = c & 7;
      const size_t rowbase = (size_t)(b * N_SEQ + nb + r) * QKFV_COLS + h * 64 + cc * 8;
      bf16x8 f8 = *(const bf16x8*)(qkfv + rowbase + 1024);
      bf16x8 v8 = *(const bf16x8*)(qkfv + rowbase + 1536);
#pragma unroll
      for (int j = 0; j < 8; ++j) {
        Ft[r * 64 + cc * 8 + j] = (float)f8[j];
        Vt[r * 64 + cc * 8 + j] = (float)v8[j];
      }
    }
    __syncthreads();
    for (int nn = 0; nn < 64; ++nn) {
      float fd = Ft[nn * 64 + d];
#pragma unroll
      for (int k = 0; k < 4; ++k)
        acc[k] += fd * *(const f32x4*)&Vt[nn * 64 + e0 + k * 4];
    }
  }
  float* dst = fvb + (size_t)bh * 4096 + d * 64 + e0;
#pragma unroll
  for (int k = 0; k < 4; ++k)
#pragma unroll
    for (int x = 0; x < 4; ++x)
      atomicAdd(dst + k * 4 + x, acc[k][x]);
}

// ---------------- pvm[bh][d][j] = sum_e fv[d][e]*w_scales[e][j] + b_scales[j] ----------------
__global__ __launch_bounds__(256) void pvmat_kernel(const float* __restrict__ fvb,
                                                    const float* __restrict__ wsc,
                                                    const float* __restrict__ bsc,
                                                    __bf16* __restrict__ pvm) {
  __shared__ alignas(16) float fvs[64 * 65];
  __shared__ alignas(16) float wst[64 * 128];
  const int t = threadIdx.x;
  const int bh = blockIdx.y;
  const int j0 = blockIdx.x * 128;
#pragma unroll
  for (int i = 0; i < 16; ++i) {
    int idx = i * 256 + t;
    fvs[(idx >> 6) * 65 + (idx & 63)] = fvb[(size_t)bh * 4096 + idx];
  }
#pragma unroll
  for (int i = 0; i < 8; ++i) {
    int c = i * 256 + t;
    int e = c >> 5, cc = c & 31;
    *(f32x4*)&wst[e * 128 + cc * 4] = *(const f32x4*)&wsc[(size_t)e * 2048 + j0 + cc * 4];
  }
  __syncthreads();
  const int d0 = (t >> 3) * 2;
  const int jb = (t & 7) * 4;
  f32x4 acc[2][4];
#pragma unroll
  for (int dd = 0; dd < 2; ++dd)
#pragma unroll
    for (int k4 = 0; k4 < 4; ++k4)
#pragma unroll
      for (int x = 0; x < 4; ++x)
        acc[dd][k4][x] = bsc[j0 + jb + k4 * 32 + x];
  for (int e = 0; e < 64; ++e) {
    float f0 = fvs[d0 * 65 + e];
    float f1 = fvs[(d0 + 1) * 65 + e];
#pragma unroll
    for (int k4 = 0; k4 < 4; ++k4) {
      f32x4 wv = *(const f32x4*)&wst[e * 128 + jb + k4 * 32];
      acc[0][k4] += f0 * wv;
      acc[1][k4] += f1 * wv;
    }
  }
#pragma unroll
  for (int dd = 0; dd < 2; ++dd) {
    __bf16* dst = pvm + (size_t)bh * 64 * 2048 + (size_t)(d0 + dd) * 2048 + j0;
#pragma unroll
    for (int k4 = 0; k4 < 4; ++k4)
#pragma unroll
      for (int x = 0; x < 4; ++x)
        dst[jb + k4 * 32 + x] = (__bf16)acc[dd][k4][x];
  }
}

// ---------------- flash attention: O = softmax(Q K^T * s) @ pv^T ----------------
#define KP 72
#define PP 72
__global__ __launch_bounds__(256) void attn_kernel(const __bf16* __restrict__ qkfv,
                                                   const __bf16* __restrict__ pvm,
                                                   __bf16* __restrict__ obuf) {
  __shared__ alignas(16) __bf16 Kbuf[64 * KP];
  __shared__ alignas(16) __bf16 Vbuf[64 * KP];
  __shared__ alignas(16) __bf16 Pbuf[128 * PP];
  const int t = threadIdx.x;
  const int w = t >> 6;
  const int lane = t & 63;
  const int ln = lane & 15;
  const int hi8 = (lane >> 4) * 8;
  const int g4 = (lane >> 4) * 4;
  const int bh = blockIdx.y;
  const int b = bh >> 3, h = bh & 7;
  const int i0 = blockIdx.x * 128;

  bf16x8 q[2][2];
#pragma unroll
  for (int m = 0; m < 2; ++m) {
    int grow = b * N_SEQ + i0 + w * 32 + m * 16 + ln;
#pragma unroll
    for (int kk = 0; kk < 2; ++kk)
      q[m][kk] = *(const bf16x8*)(qkfv + (size_t)grow * QKFV_COLS + h * 64 + kk * 32 + hi8);
  }

  f32x4 o[2][4];
  float mrow[2][4], lrow[2][4];
#pragma unroll
  for (int m = 0; m < 2; ++m)
#pragma unroll
    for (int n = 0; n < 4; ++n) o[m][n] = (f32x4){0.f, 0.f, 0.f, 0.f};
#pragma unroll
  for (int m = 0; m < 2; ++m)
#pragma unroll
    for (int r = 0; r < 4; ++r) { mrow[m][r] = -1e30f; lrow[m][r] = 0.f; }

  for (int jt = 0; jt < 32; ++jt) {
    const int j0 = jt * 64;
#pragma unroll
    for (int i = 0; i < 2; ++i) {
      int c = i * 256 + t;
      int r = c >> 3, cc = c & 7;
      bf16x8 kv = *(const bf16x8*)(qkfv + (size_t)(b * N_SEQ + j0 + r) * QKFV_COLS + 512 + h * 64 + cc * 8);
      *(bf16x8*)&Kbuf[r * KP + cc * 8] = kv;
      bf16x8 pv = *(const bf16x8*)(pvm + (size_t)(bh * 64 + r) * 2048 + j0 + cc * 8);
      *(bf16x8*)&Vbuf[r * KP + cc * 8] = pv;
    }
    __syncthreads();

    f32x4 s[2][4];
#pragma unroll
    for (int m = 0; m < 2; ++m)
#pragma unroll
      for (int jj = 0; jj < 4; ++jj) s[m][jj] = (f32x4){0.f, 0.f, 0.f, 0.f};
#pragma unroll
    for (int jj = 0; jj < 4; ++jj) {
      bf16x8 kf0 = *(const bf16x8*)&Kbuf[(jj * 16 + ln) * KP + hi8];
      bf16x8 kf1 = *(const bf16x8*)&Kbuf[(jj * 16 + ln) * KP + 32 + hi8];
#pragma unroll
      for (int m = 0; m < 2; ++m) {
        s[m][jj] = mfma16(q[m][0], kf0, s[m][jj]);
        s[m][jj] = mfma16(q[m][1], kf1, s[m][jj]);
      }
    }

#pragma unroll
    for (int m = 0; m < 2; ++m) {
#pragma unroll
      for (int r = 0; r < 4; ++r) {
        float s0 = s[m][0][r] * 0.125f, s1 = s[m][1][r] * 0.125f;
        float s2 = s[m][2][r] * 0.125f, s3 = s[m][3][r] * 0.125f;
        float tmax = fmaxf(fmaxf(s0, s1), fmaxf(s2, s3));
        for (int off = 1; off < 16; off <<= 1)
          tmax = fmaxf(tmax, __shfl_xor(tmax, off, 16));
        float mold = mrow[m][r];
        float mnew = fmaxf(mold, tmax);
        float corr = __expf(mold - mnew);
        mrow[m][r] = mnew;
        float p0 = __expf(s0 - mnew), p1 = __expf(s1 - mnew);
        float p2 = __expf(s2 - mnew), p3 = __expf(s3 - mnew);
        int prow = (w * 32 + m * 16 + g4 + r) * PP;
        Pbuf[prow + 0 + ln] = (__bf16)p0;
        Pbuf[prow + 16 + ln] = (__bf16)p1;
        Pbuf[prow + 32 + ln] = (__bf16)p2;
        Pbuf[prow + 48 + ln] = (__bf16)p3;
        float tsum = p0 + p1 + p2 + p3;
        for (int off = 1; off < 16; off <<= 1)
          tsum += __shfl_xor(tsum, off, 16);
        lrow[m][r] = lrow[m][r] * corr + tsum;
#pragma unroll
        for (int n = 0; n < 4; ++n) o[m][n][r] *= corr;
      }
    }

#pragma unroll
    for (int kk = 0; kk < 2; ++kk) {
      bf16x8 pa0 = *(const bf16x8*)&Pbuf[(w * 32 + 0 + ln) * PP + kk * 32 + hi8];
      bf16x8 pa1 = *(const bf16x8*)&Pbuf[(w * 32 + 16 + ln) * PP + kk * 32 + hi8];
#pragma unroll
      for (int nd = 0; nd < 4; ++nd) {
        bf16x8 vb = *(const bf16x8*)&Vbuf[(nd * 16 + ln) * KP + kk * 32 + hi8];
        o[0][nd] = mfma16(pa0, vb, o[0][nd]);
        o[1][nd] = mfma16(pa1, vb, o[1][nd]);
      }
    }
    __syncthreads();
  }

#pragma unroll
  for (int m = 0; m < 2; ++m)
#pragma unroll
    for (int r = 0; r < 4; ++r) {
      float inv = 1.0f / lrow[m][r];
      int grow = b * N_SEQ + i0 + w * 32 + m * 16 + g4 + r;
#pragma unroll
      for (int nd = 0; nd < 4; ++nd)
        obuf[(size_t)grow * 512 + h * 64 + nd * 16 + ln] = (__bf16)(o[m][nd][r] * inv);
    }
}

extern "C" void kernel_launch(void* const* d_in, const int* in_sizes, int n_in,
                              void* d_out, int out_size, void* d_ws, size_t ws_size,
                              hipStream_t stream) {
  (void)in_sizes; (void)n_in; (void)out_size; (void)ws_size;
  const float* x   = (const float*)d_in[0];
  const float* wqk = (const float*)d_in[1];
  const float* wsc = (const float*)d_in[2];
  const float* bsc = (const float*)d_in[3];
  const float* wo  = (const float*)d_in[4];
  const float* bo  = (const float*)d_in[5];
  float* out = (float*)d_out;

  char* p = (char*)d_ws;
  __bf16* xbf  = (__bf16*)p;  p += (size_t)8192 * 512 * 2;
  __bf16* wqT  = (__bf16*)p;  p += (size_t)2048 * 512 * 2;
  __bf16* woT  = (__bf16*)p;  p += (size_t)512 * 512 * 2;
  __bf16* qkfv = (__bf16*)p;  p += (size_t)8192 * 2048 * 2;
  float*  fvb  = (float*)p;   p += (size_t)32 * 4096 * 4;
  __bf16* pvm  = (__bf16*)p;  p += (size_t)32 * 64 * 2048 * 2;
  __bf16* obuf = (__bf16*)p;  p += (size_t)8192 * 512 * 2;

  hipMemsetAsync(fvb, 0, (size_t)32 * 4096 * 4, stream);
  cast_bf16_kernel<<<dim3(2048), dim3(256), 0, stream>>>(x, xbf, 8192 * 512 / 8);
  transpose_cast_kernel<<<dim3(512), dim3(256), 0, stream>>>(wqk, wqT, 512, 2048);
  transpose_cast_kernel<<<dim3(128), dim3(256), 0, stream>>>(wo, woT, 512, 512);
  gemm_bt_kernel<__bf16, false><<<dim3(64, 16), dim3(256), 0, stream>>>(xbf, wqT, qkfv, nullptr, 8192, 2048, 512);
  fv_kernel<<<dim3(16, 32), dim3(256), 0, stream>>>(qkfv, fvb);
  pvmat_kernel<<<dim3(16, 32), dim3(256), 0, stream>>>(fvb, wsc, bsc, pvm);
  attn_kernel<<<dim3(16, 32), dim3(256), 0, stream>>>(qkfv, pvm, obuf);
  gemm_bt_kernel<float, true><<<dim3(64, 4), dim3(256), 0, stream>>>(obuf, woT, out, bo, 8192, 512, 512);
}